// Round 6
// baseline (291.022 us; speedup 1.0000x reference)
//
#include <hip/hip_runtime.h>
#include <hip/hip_bf16.h>

// Problem constants (fixed by the reference)
#define NN   50000   // nodes
#define FF   512     // input features
#define DD   128     // embedding dim
#define CC   128     // conv channels
#define EE   20000   // hyperedges
#define MM   8       // nodes per hyperedge
#define EPSV 1e-5f

typedef __attribute__((ext_vector_type(8)))  short bfrag;    // 8 bf16
typedef __attribute__((ext_vector_type(4)))  unsigned int u32x4; // 8 bf16 packed
typedef __attribute__((ext_vector_type(16))) float f32x16;   // 32x32 MFMA acc

__device__ __forceinline__ f32x16 mfma32(u32x4 a, u32x4 b, f32x16 c) {
    return __builtin_amdgcn_mfma_f32_32x32x16_bf16(
        __builtin_bit_cast(bfrag, a), __builtin_bit_cast(bfrag, b), c, 0, 0, 0);
}

// fp32 -> bf16 bits, round-to-nearest-even (prep only)
__device__ __forceinline__ unsigned short f2bf(float f) {
    unsigned u = __builtin_bit_cast(unsigned, f);
    unsigned r = u + 0x7FFFu + ((u >> 16) & 1u);
    return (unsigned short)(r >> 16);
}
__device__ __forceinline__ float bf2f(unsigned short h) {
    unsigned u = ((unsigned)h) << 16;
    return __builtin_bit_cast(float, u);
}
__device__ __forceinline__ void split1(float a, short& hi, short& lo) {
    unsigned short h = f2bf(a);
    hi = (short)h;
    lo = (short)f2bf(a - bf2f(h));
}

// DPP butterfly add over aligned 8-lane groups (VALU pipe, no LDS/DS).
template <int CTRL>
__device__ __forceinline__ float dpp_addstep(float x) {
    const int xi = __builtin_bit_cast(int, x);
    const int yi = __builtin_amdgcn_update_dpp(xi, xi, CTRL, 0xF, 0xF, true);
    return x + __builtin_bit_cast(float, yi);
}
__device__ __forceinline__ float sum8(float x) {
    x = dpp_addstep<0xB1>(x);    // quad_perm(1,0,3,2)  : xor 1
    x = dpp_addstep<0x4E>(x);    // quad_perm(2,3,0,1)  : xor 2
    x = dpp_addstep<0x141>(x);   // row_half_mirror     : cross-quad within 8
    return x;
}

// trunc-hi / RNE-lo split of 8 floats into packed bf16 fragments.
__device__ __forceinline__ void pack_split8(const float* v, u32x4& hi, u32x4& lo) {
#pragma unroll
    for (int p = 0; p < 4; p++) {
        const unsigned u0 = __builtin_bit_cast(unsigned, v[2 * p]);
        const unsigned u1 = __builtin_bit_cast(unsigned, v[2 * p + 1]);
        const unsigned h0 = u0 & 0xFFFF0000u, h1 = u1 & 0xFFFF0000u;
        hi[p] = (u0 >> 16) | h1;
        const float r0 = v[2 * p]     - __builtin_bit_cast(float, h0);
        const float r1 = v[2 * p + 1] - __builtin_bit_cast(float, h1);
        unsigned lp;
        asm("v_cvt_pk_bf16_f32 %0, %1, %2" : "=v"(lp) : "v"(r0), "v"(r1));
        lo[p] = lp;
    }
}
// RNE pack of 8 floats into a bf16 fragment.
__device__ __forceinline__ void pack8(const float* v, u32x4& w) {
#pragma unroll
    for (int p = 0; p < 4; p++) {
        unsigned lp;
        asm("v_cvt_pk_bf16_f32 %0, %1, %2" : "=v"(lp) : "v"(v[2 * p]), "v"(v[2 * p + 1]));
        w[p] = lp;
    }
}

// ---------------------------------------------------------------------------
// K0: prep — FRAGMENT-PACKED hi/lo bf16 weights.  B[slot][col][8], slot=k/8.
//   enc:  Ep[slot 0..63][n 0..127][j]  = W_enc[slot*8+j][n]
//   edge: Wp[slot 0..31][c 0..127][j]: k=slot*8+j;
//         k<128 -> Wa[k][c] = W0 + W1/7 - (47/49) W2
//         k>=128 -> Wb[k-128][c] = -W1/7 + (12/49) W2
// ---------------------------------------------------------------------------
__global__ void prep_kernel(const float* __restrict__ W_enc,
                            const float* __restrict__ cheb_W,
                            unsigned short* __restrict__ Ep_hi,
                            unsigned short* __restrict__ Ep_lo,
                            unsigned short* __restrict__ Wp_hi,
                            unsigned short* __restrict__ Wp_lo) {
    const int tid = blockIdx.x * blockDim.x + threadIdx.x;
    const int stride = gridDim.x * blockDim.x;
    for (int p = tid; p < 64 * 128; p += stride) {
        const int slot = p >> 7, n = p & 127;
        bfrag fh, fl;
#pragma unroll
        for (int j = 0; j < 8; j++) {
            const float v = W_enc[(size_t)(slot * 8 + j) * DD + n];
            short h, lo; split1(v, h, lo);
            fh[j] = h; fl[j] = lo;
        }
        *(bfrag*)&Ep_hi[(size_t)p * 8] = fh;
        *(bfrag*)&Ep_lo[(size_t)p * 8] = fl;
    }
    const float c1 = 1.0f / 7.0f;
    const float c2 = -47.0f / 49.0f;
    const float c3 = -1.0f / 7.0f;
    const float c4 = 12.0f / 49.0f;
    for (int p = tid; p < 32 * 128; p += stride) {
        const int slot = p >> 7, c = p & 127;
        bfrag fh, fl;
#pragma unroll
        for (int j = 0; j < 8; j++) {
            const int k = slot * 8 + j;
            float v;
            if (k < DD) {
                v = cheb_W[0 * DD * CC + k * CC + c]
                  + c1 * cheb_W[1 * DD * CC + k * CC + c]
                  + c2 * cheb_W[2 * DD * CC + k * CC + c];
            } else {
                const int d = k - DD;
                v = c3 * cheb_W[1 * DD * CC + d * CC + c]
                  + c4 * cheb_W[2 * DD * CC + d * CC + c];
            }
            short h, lo; split1(v, h, lo);
            fh[j] = h; fl[j] = lo;
        }
        *(bfrag*)&Wp_hi[(size_t)p * 8] = fh;
        *(bfrag*)&Wp_lo[(size_t)p * 8] = fl;
    }
}

// ---------------------------------------------------------------------------
// K1: encoder GEMM  x = clip(pos @ W_enc + b_enc, -1, 1)   [50000,128] fp32
// 128 thr = 2 waves; block = one 32-row m-tile; wave w = cols w*64..w*64+63
// (2 n-tiles, acc[2]). Depth-2 register prefetch of A chunks (static idx).
// Grid 1563 -> ~6 blocks/CU = 12 waves/CU. No LDS, no barriers.
// ---------------------------------------------------------------------------
__global__ __launch_bounds__(128, 4) void enc_kernel(
        const float* __restrict__ pos,
        const unsigned short* __restrict__ Ep_hi,
        const unsigned short* __restrict__ Ep_lo,
        const float* __restrict__ b_enc,
        float* __restrict__ x) {
    const int t = threadIdx.x;
    const int w = t >> 6, l = t & 63, l31 = l & 31, lg2 = l >> 5;

    int arow = blockIdx.x * 32 + l31;
    if (arow >= NN) arow = NN - 1;                 // clamp (writes guarded)
    const float* aBase = pos + (size_t)arow * FF + lg2 * 8;

    f32x16 acc[2];
#pragma unroll
    for (int ntl = 0; ntl < 2; ntl++)
#pragma unroll
        for (int i = 0; i < 16; i++) acc[ntl][i] = 0.f;

    auto body = [&](float4 a0, float4 a1, int ks) {
        const float av[8] = {a0.x, a0.y, a0.z, a0.w, a1.x, a1.y, a1.z, a1.w};
        u32x4 ahi, alo;
        pack_split8(av, ahi, alo);
        const int slot = ks * 2 + lg2;
#pragma unroll
        for (int ntl = 0; ntl < 2; ntl++) {
            const int col = w * 64 + ntl * 32 + l31;
            const size_t boff = ((size_t)slot * 128 + col) * 8;
            const u32x4 bhi = *(const u32x4*)(Ep_hi + boff);
            const u32x4 blo = *(const u32x4*)(Ep_lo + boff);
            acc[ntl] = mfma32(ahi, bhi, acc[ntl]);
            acc[ntl] = mfma32(ahi, blo, acc[ntl]);
            acc[ntl] = mfma32(alo, bhi, acc[ntl]);
        }
    };

    // A chunk for ks is 8 floats at aBase + ks*16. Depth-2 prefetch, static.
    float4 pa0 = *(const float4*)(aBase);
    float4 pa1 = *(const float4*)(aBase + 4);
    float4 pb0 = *(const float4*)(aBase + 16);
    float4 pb1 = *(const float4*)(aBase + 20);
    for (int ks = 0; ks < 32; ks += 2) {
        const float4 c0 = pa0, c1 = pa1;
        if (ks + 2 < 32) {
            pa0 = *(const float4*)(aBase + (ks + 2) * 16);
            pa1 = *(const float4*)(aBase + (ks + 2) * 16 + 4);
        }
        body(c0, c1, ks);
        const float4 d0 = pb0, d1 = pb1;
        if (ks + 3 < 32) {
            pb0 = *(const float4*)(aBase + (ks + 3) * 16);
            pb1 = *(const float4*)(aBase + (ks + 3) * 16 + 4);
        }
        body(d0, d1, ks + 1);
    }

    // epilogue: C/D col = lane&31, row = (r&3) + 8*(r>>2) + 4*lg2
    const int brow = blockIdx.x * 32;
#pragma unroll
    for (int ntl = 0; ntl < 2; ntl++) {
        const int col = w * 64 + ntl * 32 + l31;
        const float bias = b_enc[col];
#pragma unroll
        for (int r = 0; r < 16; r++) {
            const int row = brow + (r & 3) + 8 * (r >> 2) + 4 * lg2;
            if (row < NN) {
                const float v = acc[ntl][r] + bias;
                x[(size_t)row * DD + col] = fminf(1.0f, fmaxf(-1.0f, v));
            }
        }
    }
}

// ---------------------------------------------------------------------------
// K2: fused edge kernel — wave-autonomous, zero LDS, zero barriers.
// 256 thr = 4 waves; wave owns 4 edges (32-row m-tile) x all 4 n-tiles.
// ONE-PASS GraphNorm stats: s=sum8(v), q=sum8(v^2) in parallel DPP chains;
// var = q/8 - a(2-a)m^2. Colsum closed form S = 8*(sc*m*(1-a)+b).
// Depth-2 register prefetch of gathered x chunks. B fragment-packed from L2.
// ---------------------------------------------------------------------------
__global__ __launch_bounds__(256, 4) void edge_kernel(
        const float* __restrict__ x,
        const int* __restrict__ members,
        const unsigned short* __restrict__ Wp_hi,
        const unsigned short* __restrict__ Wp_lo,
        const float* __restrict__ gn_gamma,
        const float* __restrict__ gn_beta,
        const float* __restrict__ gn_alpha,
        const float* __restrict__ cheb_b,
        const float* __restrict__ lin_W,
        const float* __restrict__ lin_b,
        float* __restrict__ out) {
    const int t = threadIdx.x;
    const int w = t >> 6, l = t & 63, l31 = l & 31, lg2 = l >> 5;

    const int node = members[blockIdx.x * 128 + w * 32 + l31];
    const float* xrow = x + (size_t)node * DD + lg2 * 8;

    f32x16 acc[4];
#pragma unroll
    for (int nt = 0; nt < 4; nt++)
#pragma unroll
        for (int i = 0; i < 16; i++) acc[nt][i] = 0.f;

    auto body = [&](float4 a0, float4 a1, int ks) {
        const int koff = ks * 16 + lg2 * 8;      // d-chunk 0..127
        // params first (independent loads, L1-hot)
        const float4 al0 = *(const float4*)(gn_alpha + koff);
        const float4 al1 = *(const float4*)(gn_alpha + koff + 4);
        const float4 g0  = *(const float4*)(gn_gamma + koff);
        const float4 g1  = *(const float4*)(gn_gamma + koff + 4);
        const float4 b0  = *(const float4*)(gn_beta + koff);
        const float4 b1  = *(const float4*)(gn_beta + koff + 4);
        const float al[8] = {al0.x, al0.y, al0.z, al0.w, al1.x, al1.y, al1.z, al1.w};
        const float gm[8] = {g0.x, g0.y, g0.z, g0.w, g1.x, g1.y, g1.z, g1.w};
        const float bt[8] = {b0.x, b0.y, b0.z, b0.w, b1.x, b1.y, b1.z, b1.w};

        const float v[8] = {a0.x, a0.y, a0.z, a0.w, a1.x, a1.y, a1.z, a1.w};
        float s[8], q[8];
#pragma unroll
        for (int j = 0; j < 8; j++) { s[j] = v[j]; q[j] = v[j] * v[j]; }
        // two independent butterfly chains — interleaved by the scheduler
#pragma unroll
        for (int j = 0; j < 8; j++) s[j] = dpp_addstep<0xB1>(s[j]);
#pragma unroll
        for (int j = 0; j < 8; j++) q[j] = dpp_addstep<0xB1>(q[j]);
#pragma unroll
        for (int j = 0; j < 8; j++) s[j] = dpp_addstep<0x4E>(s[j]);
#pragma unroll
        for (int j = 0; j < 8; j++) q[j] = dpp_addstep<0x4E>(q[j]);
#pragma unroll
        for (int j = 0; j < 8; j++) s[j] = dpp_addstep<0x141>(s[j]);
#pragma unroll
        for (int j = 0; j < 8; j++) q[j] = dpp_addstep<0x141>(q[j]);

        float nv[8], sv[8];
#pragma unroll
        for (int j = 0; j < 8; j++) {
            const float m   = s[j] * 0.125f;
            const float var = q[j] * 0.125f - al[j] * (2.0f - al[j]) * m * m;
            const float sc  = gm[j] * rsqrtf(var + EPSV);
            nv[j] = sc * (v[j] - al[j] * m) + bt[j];
            sv[j] = 8.0f * (sc * m * (1.0f - al[j]) + bt[j]);
        }
        u32x4 ahi, alo, shi;
        pack_split8(nv, ahi, alo);
        pack8(sv, shi);

        const int slotN = ks * 2 + lg2;          // norm half k = 0..127
        const int slotS = 16 + slotN;            // S half    k = 128..255
#pragma unroll
        for (int nt = 0; nt < 4; nt++) {
            const int col = nt * 32 + l31;
            const size_t offN = ((size_t)slotN * 128 + col) * 8;
            const size_t offS = ((size_t)slotS * 128 + col) * 8;
            const u32x4 wahi = *(const u32x4*)(Wp_hi + offN);
            const u32x4 walo = *(const u32x4*)(Wp_lo + offN);
            const u32x4 wbh  = *(const u32x4*)(Wp_hi + offS);
            acc[nt] = mfma32(ahi, wahi, acc[nt]);
            acc[nt] = mfma32(ahi, walo, acc[nt]);
            acc[nt] = mfma32(alo, wahi, acc[nt]);
            acc[nt] = mfma32(shi, wbh,  acc[nt]);
        }
    };

    // x chunk for ks is 8 floats at xrow + ks*16. Depth-2 prefetch, static.
    float4 pa0 = *(const float4*)(xrow);
    float4 pa1 = *(const float4*)(xrow + 4);
    float4 pb0 = *(const float4*)(xrow + 16);
    float4 pb1 = *(const float4*)(xrow + 20);
    for (int ks = 0; ks < 8; ks += 2) {
        const float4 c0 = pa0, c1 = pa1;
        if (ks + 2 < 8) {
            pa0 = *(const float4*)(xrow + (ks + 2) * 16);
            pa1 = *(const float4*)(xrow + (ks + 2) * 16 + 4);
        }
        body(c0, c1, ks);
        const float4 d0 = pb0, d1 = pb1;
        if (ks + 3 < 8) {
            pb0 = *(const float4*)(xrow + (ks + 3) * 16);
            pb1 = *(const float4*)(xrow + (ks + 3) * 16 + 4);
        }
        body(d0, d1, ks + 1);
    }

    // ---- epilogue: reg r of acc[nt]: edge e = r>>2, member (r&3)+4*lg2,
    // col = nt*32 + l31. Pool 8 member rows = 4 regs + shfl_xor(32).
    float p[4] = {0.f, 0.f, 0.f, 0.f};
#pragma unroll
    for (int nt = 0; nt < 4; nt++) {
        const int col = nt * 32 + l31;
        const float bias = cheb_b[col];
        const float w1 = lin_W[col], w2 = lin_W[DD + col];
#pragma unroll
        for (int e = 0; e < 4; e++) {
            float mx = -2.f, mn = 2.f, ssq = 0.f;
#pragma unroll
            for (int q2 = 0; q2 < 4; q2++) {
                float h = acc[nt][e * 4 + q2] + bias;
                h = fminf(1.0f, fmaxf(-1.0f, h));
                mx = fmaxf(mx, h); mn = fminf(mn, h); ssq += h * h;
            }
            mx = fmaxf(mx, __shfl_xor(mx, 32));
            mn = fminf(mn, __shfl_xor(mn, 32));
            ssq += __shfl_xor(ssq, 32);
            p[e] += (mx - mn) * w1 + sqrtf(ssq * 0.125f) * w2;
        }
    }
#pragma unroll
    for (int mk = 1; mk <= 16; mk <<= 1)
#pragma unroll
        for (int e = 0; e < 4; e++) p[e] += __shfl_xor(p[e], mk);
    if (l == 0) {
        const float b0 = lin_b[0];
#pragma unroll
        for (int e = 0; e < 4; e++) {
            const float z = p[e] + b0;
            out[blockIdx.x * 16 + w * 4 + e] = 1.0f / (1.0f + expf(-z));
        }
    }
}

// ---------------------------------------------------------------------------
extern "C" void kernel_launch(void* const* d_in, const int* in_sizes, int n_in,
                              void* d_out, int out_size, void* d_ws, size_t ws_size,
                              hipStream_t stream) {
    const float* pos    = (const float*)d_in[0];
    const float* W_enc  = (const float*)d_in[1];
    const float* b_enc  = (const float*)d_in[2];
    const float* gammaP = (const float*)d_in[3];
    const float* betaP  = (const float*)d_in[4];
    const float* alphaP = (const float*)d_in[5];
    const float* cheb_W = (const float*)d_in[6];
    const float* cheb_b = (const float*)d_in[7];
    const float* lin_W  = (const float*)d_in[8];
    const float* lin_b  = (const float*)d_in[9];
    const int*   members = (const int*)d_in[10];
    // d_in[11] edge_index, d_in[12] batch: fixed 8-clique; unused.
    float* out = (float*)d_out;

    char* ws = (char*)d_ws;
    float* x = (float*)ws;                                     // 25,600,000 B
    unsigned short* Ep_hi = (unsigned short*)(ws + 25600000);  // 64*128*8
    unsigned short* Ep_lo = Ep_hi + 64 * 128 * 8;
    unsigned short* Wp_hi = Ep_lo + 64 * 128 * 8;              // 32*128*8
    unsigned short* Wp_lo = Wp_hi + 32 * 128 * 8;

    prep_kernel<<<32, 256, 0, stream>>>(W_enc, cheb_W, Ep_hi, Ep_lo, Wp_hi, Wp_lo);
    enc_kernel<<<(NN + 31) / 32, 128, 0, stream>>>(pos, Ep_hi, Ep_lo, b_enc, x);
    edge_kernel<<<EE / 16, 256, 0, stream>>>(x, members, Wp_hi, Wp_lo,
                                             gammaP, betaP, alphaP, cheb_b, lin_W, lin_b, out);
}

// Round 7
// 264.581 us; speedup vs baseline: 1.0999x; 1.0999x over previous
//
#include <hip/hip_runtime.h>
#include <hip/hip_bf16.h>

// Problem constants (fixed by the reference)
#define NN   50000   // nodes
#define FF   512     // input features
#define DD   128     // embedding dim
#define CC   128     // conv channels
#define EE   20000   // hyperedges
#define MM   8       // nodes per hyperedge
#define EPSV 1e-5f

typedef __attribute__((ext_vector_type(8)))  short bfrag;    // 8 bf16
typedef __attribute__((ext_vector_type(4)))  unsigned int u32x4; // 8 bf16 packed
typedef __attribute__((ext_vector_type(16))) float f32x16;   // 32x32 MFMA acc

__device__ __forceinline__ f32x16 mfma32(u32x4 a, u32x4 b, f32x16 c) {
    return __builtin_amdgcn_mfma_f32_32x32x16_bf16(
        __builtin_bit_cast(bfrag, a), __builtin_bit_cast(bfrag, b), c, 0, 0, 0);
}

// fp32 -> bf16 bits, round-to-nearest-even (prep only)
__device__ __forceinline__ unsigned short f2bf(float f) {
    unsigned u = __builtin_bit_cast(unsigned, f);
    unsigned r = u + 0x7FFFu + ((u >> 16) & 1u);
    return (unsigned short)(r >> 16);
}
__device__ __forceinline__ float bf2f(unsigned short h) {
    unsigned u = ((unsigned)h) << 16;
    return __builtin_bit_cast(float, u);
}
__device__ __forceinline__ void split1(float a, short& hi, short& lo) {
    unsigned short h = f2bf(a);
    hi = (short)h;
    lo = (short)f2bf(a - bf2f(h));
}

// DPP butterfly add over aligned 8-lane groups (VALU pipe, no LDS/DS).
template <int CTRL>
__device__ __forceinline__ float dpp_addstep(float x) {
    const int xi = __builtin_bit_cast(int, x);
    const int yi = __builtin_amdgcn_update_dpp(xi, xi, CTRL, 0xF, 0xF, true);
    return x + __builtin_bit_cast(float, yi);
}

// trunc-hi / RNE-lo split of 8 floats into packed bf16 fragments.
__device__ __forceinline__ void pack_split8(const float* v, u32x4& hi, u32x4& lo) {
#pragma unroll
    for (int p = 0; p < 4; p++) {
        const unsigned u0 = __builtin_bit_cast(unsigned, v[2 * p]);
        const unsigned u1 = __builtin_bit_cast(unsigned, v[2 * p + 1]);
        const unsigned h0 = u0 & 0xFFFF0000u, h1 = u1 & 0xFFFF0000u;
        hi[p] = (u0 >> 16) | h1;
        const float r0 = v[2 * p]     - __builtin_bit_cast(float, h0);
        const float r1 = v[2 * p + 1] - __builtin_bit_cast(float, h1);
        unsigned lp;
        asm("v_cvt_pk_bf16_f32 %0, %1, %2" : "=v"(lp) : "v"(r0), "v"(r1));
        lo[p] = lp;
    }
}
// RNE pack of 8 floats into a bf16 fragment.
__device__ __forceinline__ void pack8(const float* v, u32x4& w) {
#pragma unroll
    for (int p = 0; p < 4; p++) {
        unsigned lp;
        asm("v_cvt_pk_bf16_f32 %0, %1, %2" : "=v"(lp) : "v"(v[2 * p]), "v"(v[2 * p + 1]));
        w[p] = lp;
    }
}

// ---------------------------------------------------------------------------
// K0: prep — FRAGMENT-PACKED hi/lo bf16 weights.  B[slot][col][8], slot=k/8.
//   enc:  Ep[slot 0..63][n 0..127][j]  = W_enc[slot*8+j][n]
//   edge: Wp[slot 0..31][c 0..127][j]: k=slot*8+j;
//         k<128 -> Wa[k][c] = W0 + W1/7 - (47/49) W2
//         k>=128 -> Wb[k-128][c] = -W1/7 + (12/49) W2
// ---------------------------------------------------------------------------
__global__ void prep_kernel(const float* __restrict__ W_enc,
                            const float* __restrict__ cheb_W,
                            unsigned short* __restrict__ Ep_hi,
                            unsigned short* __restrict__ Ep_lo,
                            unsigned short* __restrict__ Wp_hi,
                            unsigned short* __restrict__ Wp_lo) {
    const int tid = blockIdx.x * blockDim.x + threadIdx.x;
    const int stride = gridDim.x * blockDim.x;
    for (int p = tid; p < 64 * 128; p += stride) {
        const int slot = p >> 7, n = p & 127;
        bfrag fh, fl;
#pragma unroll
        for (int j = 0; j < 8; j++) {
            const float v = W_enc[(size_t)(slot * 8 + j) * DD + n];
            short h, lo; split1(v, h, lo);
            fh[j] = h; fl[j] = lo;
        }
        *(bfrag*)&Ep_hi[(size_t)p * 8] = fh;
        *(bfrag*)&Ep_lo[(size_t)p * 8] = fl;
    }
    const float c1 = 1.0f / 7.0f;
    const float c2 = -47.0f / 49.0f;
    const float c3 = -1.0f / 7.0f;
    const float c4 = 12.0f / 49.0f;
    for (int p = tid; p < 32 * 128; p += stride) {
        const int slot = p >> 7, c = p & 127;
        bfrag fh, fl;
#pragma unroll
        for (int j = 0; j < 8; j++) {
            const int k = slot * 8 + j;
            float v;
            if (k < DD) {
                v = cheb_W[0 * DD * CC + k * CC + c]
                  + c1 * cheb_W[1 * DD * CC + k * CC + c]
                  + c2 * cheb_W[2 * DD * CC + k * CC + c];
            } else {
                const int d = k - DD;
                v = c3 * cheb_W[1 * DD * CC + d * CC + c]
                  + c4 * cheb_W[2 * DD * CC + d * CC + c];
            }
            short h, lo; split1(v, h, lo);
            fh[j] = h; fl[j] = lo;
        }
        *(bfrag*)&Wp_hi[(size_t)p * 8] = fh;
        *(bfrag*)&Wp_lo[(size_t)p * 8] = fl;
    }
}

// ---------------------------------------------------------------------------
// K1: encoder GEMM  x = clip(pos @ W_enc + b_enc, -1, 1)   [50000,128] fp32
// 256 thr = 4 waves = 2 m-tiles (32 rows) x 2 col-halves (64 cols, acc[2]).
// Block tile 64x128, grid 782 -> 3 blk/CU = 12 waves/CU. Depth-4 register
// prefetch ring (static indices). No LDS, no barriers.
// ---------------------------------------------------------------------------
__global__ __launch_bounds__(256, 4) void enc_kernel(
        const float* __restrict__ pos,
        const unsigned short* __restrict__ Ep_hi,
        const unsigned short* __restrict__ Ep_lo,
        const float* __restrict__ b_enc,
        float* __restrict__ x) {
    const int t = threadIdx.x;
    const int w = t >> 6, l = t & 63, l31 = l & 31, lg2 = l >> 5;
    const int wm = w & 1, wn = w >> 1;           // m-tile, col-half

    int arow = blockIdx.x * 64 + wm * 32 + l31;
    if (arow >= NN) arow = NN - 1;               // clamp (writes guarded)
    const float* aBase = pos + (size_t)arow * FF + lg2 * 8;

    f32x16 acc[2];
#pragma unroll
    for (int ntl = 0; ntl < 2; ntl++)
#pragma unroll
        for (int i = 0; i < 16; i++) acc[ntl][i] = 0.f;

    auto body = [&](float4 a0, float4 a1, int ks) {
        const float av[8] = {a0.x, a0.y, a0.z, a0.w, a1.x, a1.y, a1.z, a1.w};
        u32x4 ahi, alo;
        pack_split8(av, ahi, alo);
        const int slot = ks * 2 + lg2;
#pragma unroll
        for (int ntl = 0; ntl < 2; ntl++) {
            const int col = wn * 64 + ntl * 32 + l31;
            const size_t boff = ((size_t)slot * 128 + col) * 8;
            const u32x4 bhi = *(const u32x4*)(Ep_hi + boff);
            const u32x4 blo = *(const u32x4*)(Ep_lo + boff);
            acc[ntl] = mfma32(ahi, bhi, acc[ntl]);
            acc[ntl] = mfma32(ahi, blo, acc[ntl]);
            acc[ntl] = mfma32(alo, bhi, acc[ntl]);
        }
    };

    // A chunk for ks: 8 floats at aBase + ks*16. Depth-4 ring, all static.
    float4 q0a = *(const float4*)(aBase +  0), q0b = *(const float4*)(aBase +  4);
    float4 q1a = *(const float4*)(aBase + 16), q1b = *(const float4*)(aBase + 20);
    float4 q2a = *(const float4*)(aBase + 32), q2b = *(const float4*)(aBase + 36);
    float4 q3a = *(const float4*)(aBase + 48), q3b = *(const float4*)(aBase + 52);
    for (int ks = 0; ks < 32; ks += 4) {
        float4 c0, c1;
        c0 = q0a; c1 = q0b;
        if (ks + 4 < 32) { q0a = *(const float4*)(aBase + (ks + 4) * 16);
                           q0b = *(const float4*)(aBase + (ks + 4) * 16 + 4); }
        body(c0, c1, ks);
        c0 = q1a; c1 = q1b;
        if (ks + 5 < 32) { q1a = *(const float4*)(aBase + (ks + 5) * 16);
                           q1b = *(const float4*)(aBase + (ks + 5) * 16 + 4); }
        body(c0, c1, ks + 1);
        c0 = q2a; c1 = q2b;
        if (ks + 6 < 32) { q2a = *(const float4*)(aBase + (ks + 6) * 16);
                           q2b = *(const float4*)(aBase + (ks + 6) * 16 + 4); }
        body(c0, c1, ks + 2);
        c0 = q3a; c1 = q3b;
        if (ks + 7 < 32) { q3a = *(const float4*)(aBase + (ks + 7) * 16);
                           q3b = *(const float4*)(aBase + (ks + 7) * 16 + 4); }
        body(c0, c1, ks + 3);
    }

    // epilogue: C/D col = lane&31, row = (r&3) + 8*(r>>2) + 4*lg2
    const int brow = blockIdx.x * 64 + wm * 32;
#pragma unroll
    for (int ntl = 0; ntl < 2; ntl++) {
        const int col = wn * 64 + ntl * 32 + l31;
        const float bias = b_enc[col];
#pragma unroll
        for (int r = 0; r < 16; r++) {
            const int row = brow + (r & 3) + 8 * (r >> 2) + 4 * lg2;
            if (row < NN) {
                const float v = acc[ntl][r] + bias;
                x[(size_t)row * DD + col] = fminf(1.0f, fmaxf(-1.0f, v));
            }
        }
    }
}

// ---------------------------------------------------------------------------
// K2: fused edge kernel — wave-autonomous, zero LDS, zero barriers.
// 256 thr = 4 waves; wave owns 4 edges (32-row m-tile) x all 4 n-tiles.
// ONE-PASS GraphNorm stats: s=sum8(v), q=sum8(v^2) in parallel DPP chains;
// var = q/8 - a(2-a)m^2. Colsum closed form S = 8*(sc*m*(1-a)+b).
// launch_bounds(256,3): 170-reg budget = 64 AGPR acc + ~106 VGPR -> NO SPILL.
// ---------------------------------------------------------------------------
__global__ __launch_bounds__(256, 3) void edge_kernel(
        const float* __restrict__ x,
        const int* __restrict__ members,
        const unsigned short* __restrict__ Wp_hi,
        const unsigned short* __restrict__ Wp_lo,
        const float* __restrict__ gn_gamma,
        const float* __restrict__ gn_beta,
        const float* __restrict__ gn_alpha,
        const float* __restrict__ cheb_b,
        const float* __restrict__ lin_W,
        const float* __restrict__ lin_b,
        float* __restrict__ out) {
    const int t = threadIdx.x;
    const int w = t >> 6, l = t & 63, l31 = l & 31, lg2 = l >> 5;

    const int node = members[blockIdx.x * 128 + w * 32 + l31];
    const float* xrow = x + (size_t)node * DD + lg2 * 8;

    f32x16 acc[4];
#pragma unroll
    for (int nt = 0; nt < 4; nt++)
#pragma unroll
        for (int i = 0; i < 16; i++) acc[nt][i] = 0.f;

    auto body = [&](float4 a0, float4 a1, int ks) {
        const int koff = ks * 16 + lg2 * 8;      // d-chunk 0..127
        const float4 al0 = *(const float4*)(gn_alpha + koff);
        const float4 al1 = *(const float4*)(gn_alpha + koff + 4);
        const float4 g0  = *(const float4*)(gn_gamma + koff);
        const float4 g1  = *(const float4*)(gn_gamma + koff + 4);
        const float4 b0  = *(const float4*)(gn_beta + koff);
        const float4 b1  = *(const float4*)(gn_beta + koff + 4);
        const float al[8] = {al0.x, al0.y, al0.z, al0.w, al1.x, al1.y, al1.z, al1.w};
        const float gm[8] = {g0.x, g0.y, g0.z, g0.w, g1.x, g1.y, g1.z, g1.w};
        const float bt[8] = {b0.x, b0.y, b0.z, b0.w, b1.x, b1.y, b1.z, b1.w};

        const float v[8] = {a0.x, a0.y, a0.z, a0.w, a1.x, a1.y, a1.z, a1.w};
        float s[8], q[8];
#pragma unroll
        for (int j = 0; j < 8; j++) { s[j] = v[j]; q[j] = v[j] * v[j]; }
        // two independent butterfly chains — interleaved by the scheduler
#pragma unroll
        for (int j = 0; j < 8; j++) s[j] = dpp_addstep<0xB1>(s[j]);
#pragma unroll
        for (int j = 0; j < 8; j++) q[j] = dpp_addstep<0xB1>(q[j]);
#pragma unroll
        for (int j = 0; j < 8; j++) s[j] = dpp_addstep<0x4E>(s[j]);
#pragma unroll
        for (int j = 0; j < 8; j++) q[j] = dpp_addstep<0x4E>(q[j]);
#pragma unroll
        for (int j = 0; j < 8; j++) s[j] = dpp_addstep<0x141>(s[j]);
#pragma unroll
        for (int j = 0; j < 8; j++) q[j] = dpp_addstep<0x141>(q[j]);

        float nv[8], sv[8];
#pragma unroll
        for (int j = 0; j < 8; j++) {
            const float m   = s[j] * 0.125f;
            const float var = q[j] * 0.125f - al[j] * (2.0f - al[j]) * m * m;
            const float sc  = gm[j] * rsqrtf(var + EPSV);
            nv[j] = sc * (v[j] - al[j] * m) + bt[j];
            sv[j] = 8.0f * (sc * m * (1.0f - al[j]) + bt[j]);
        }
        u32x4 ahi, alo, shi;
        pack_split8(nv, ahi, alo);
        pack8(sv, shi);

        const int slotN = ks * 2 + lg2;          // norm half k = 0..127
        const int slotS = 16 + slotN;            // S half    k = 128..255
#pragma unroll
        for (int nt = 0; nt < 4; nt++) {
            const int col = nt * 32 + l31;
            const size_t offN = ((size_t)slotN * 128 + col) * 8;
            const size_t offS = ((size_t)slotS * 128 + col) * 8;
            const u32x4 wahi = *(const u32x4*)(Wp_hi + offN);
            const u32x4 walo = *(const u32x4*)(Wp_lo + offN);
            const u32x4 wbh  = *(const u32x4*)(Wp_hi + offS);
            acc[nt] = mfma32(ahi, wahi, acc[nt]);
            acc[nt] = mfma32(ahi, walo, acc[nt]);
            acc[nt] = mfma32(alo, wahi, acc[nt]);
            acc[nt] = mfma32(shi, wbh,  acc[nt]);
        }
    };

    // x chunk for ks: 8 floats at xrow + ks*16. Depth-2 prefetch, static.
    float4 pa0 = *(const float4*)(xrow);
    float4 pa1 = *(const float4*)(xrow + 4);
    float4 pb0 = *(const float4*)(xrow + 16);
    float4 pb1 = *(const float4*)(xrow + 20);
    for (int ks = 0; ks < 8; ks += 2) {
        const float4 c0 = pa0, c1 = pa1;
        if (ks + 2 < 8) {
            pa0 = *(const float4*)(xrow + (ks + 2) * 16);
            pa1 = *(const float4*)(xrow + (ks + 2) * 16 + 4);
        }
        body(c0, c1, ks);
        const float4 d0 = pb0, d1 = pb1;
        if (ks + 3 < 8) {
            pb0 = *(const float4*)(xrow + (ks + 3) * 16);
            pb1 = *(const float4*)(xrow + (ks + 3) * 16 + 4);
        }
        body(d0, d1, ks + 1);
    }

    // ---- epilogue: reg r of acc[nt]: edge e = r>>2, member (r&3)+4*lg2,
    // col = nt*32 + l31. Pool 8 member rows = 4 regs + shfl_xor(32).
    float p[4] = {0.f, 0.f, 0.f, 0.f};
#pragma unroll
    for (int nt = 0; nt < 4; nt++) {
        const int col = nt * 32 + l31;
        const float bias = cheb_b[col];
        const float w1 = lin_W[col], w2 = lin_W[DD + col];
#pragma unroll
        for (int e = 0; e < 4; e++) {
            float mx = -2.f, mn = 2.f, ssq = 0.f;
#pragma unroll
            for (int q2 = 0; q2 < 4; q2++) {
                float h = acc[nt][e * 4 + q2] + bias;
                h = fminf(1.0f, fmaxf(-1.0f, h));
                mx = fmaxf(mx, h); mn = fminf(mn, h); ssq += h * h;
            }
            mx = fmaxf(mx, __shfl_xor(mx, 32));
            mn = fminf(mn, __shfl_xor(mn, 32));
            ssq += __shfl_xor(ssq, 32);
            p[e] += (mx - mn) * w1 + sqrtf(ssq * 0.125f) * w2;
        }
    }
#pragma unroll
    for (int mk = 1; mk <= 16; mk <<= 1)
#pragma unroll
        for (int e = 0; e < 4; e++) p[e] += __shfl_xor(p[e], mk);
    if (l == 0) {
        const float b0 = lin_b[0];
#pragma unroll
        for (int e = 0; e < 4; e++) {
            const float z = p[e] + b0;
            out[blockIdx.x * 16 + w * 4 + e] = 1.0f / (1.0f + expf(-z));
        }
    }
}

// ---------------------------------------------------------------------------
extern "C" void kernel_launch(void* const* d_in, const int* in_sizes, int n_in,
                              void* d_out, int out_size, void* d_ws, size_t ws_size,
                              hipStream_t stream) {
    const float* pos    = (const float*)d_in[0];
    const float* W_enc  = (const float*)d_in[1];
    const float* b_enc  = (const float*)d_in[2];
    const float* gammaP = (const float*)d_in[3];
    const float* betaP  = (const float*)d_in[4];
    const float* alphaP = (const float*)d_in[5];
    const float* cheb_W = (const float*)d_in[6];
    const float* cheb_b = (const float*)d_in[7];
    const float* lin_W  = (const float*)d_in[8];
    const float* lin_b  = (const float*)d_in[9];
    const int*   members = (const int*)d_in[10];
    // d_in[11] edge_index, d_in[12] batch: fixed 8-clique; unused.
    float* out = (float*)d_out;

    char* ws = (char*)d_ws;
    float* x = (float*)ws;                                     // 25,600,000 B
    unsigned short* Ep_hi = (unsigned short*)(ws + 25600000);  // 64*128*8
    unsigned short* Ep_lo = Ep_hi + 64 * 128 * 8;
    unsigned short* Wp_hi = Ep_lo + 64 * 128 * 8;              // 32*128*8
    unsigned short* Wp_lo = Wp_hi + 32 * 128 * 8;

    prep_kernel<<<32, 256, 0, stream>>>(W_enc, cheb_W, Ep_hi, Ep_lo, Wp_hi, Wp_lo);
    enc_kernel<<<(NN + 63) / 64, 256, 0, stream>>>(pos, Ep_hi, Ep_lo, b_enc, x);
    edge_kernel<<<EE / 16, 256, 0, stream>>>(x, members, Wp_hi, Wp_lo,
                                             gammaP, betaP, alphaP, cheb_b, lin_W, lin_b, out);
}